// Round 15
// baseline (5439.527 us; speedup 1.0000x reference)
//
#include <hip/hip_runtime.h>
#include <hip/hip_bf16.h>

#define BB 64
#define TT 512
#define DD 1024
#define UU 1024

typedef __attribute__((ext_vector_type(8))) short short8;
typedef __attribute__((ext_vector_type(4))) float f32x4;
typedef unsigned long long ull;

static __device__ __forceinline__ unsigned short f2bf(float f) {
    unsigned int u = __float_as_uint(f);
    unsigned int r = (u + 0x7fffu + ((u >> 16) & 1u)) >> 16;   // RNE
    return (unsigned short)r;
}
static __device__ __forceinline__ float bf2f(unsigned short s) {
    return __uint_as_float(((unsigned int)s) << 16);
}
static __device__ __forceinline__ float fsig(float x) {
    return 1.0f / (1.0f + __expf(-x));
}
static __device__ __forceinline__ float ftanh(float x) {
    float e = __expf(-2.0f * fabsf(x));
    float r = (1.0f - e) / (1.0f + e);
    return __builtin_copysignf(r, x);
}

// ---------------------------------------------------------------------------
// Pack a logical (1024 x 4096) weight into MFMA B-fragment layout (see r2).
// ---------------------------------------------------------------------------
__global__ __launch_bounds__(256) void pack_w(
    const float* __restrict__ w0, const float* __restrict__ w1,
    const float* __restrict__ w2, const float* __restrict__ w3,
    short* __restrict__ out)
{
    int tid = blockIdx.x * 256 + threadIdx.x;
    int lane = tid & 63;
    int kb = (tid >> 6) & 31;
    int n16 = tid >> 11;
    int col = (n16 << 4) + (lane & 15);
    int g = col >> 10, u = col & 1023;
    const float* __restrict__ src = (g == 0) ? w0 : (g == 1) ? w1 : (g == 2) ? w2 : w3;
    int kbase = kb * 32 + ((lane >> 4) << 3);
    short8 p;
#pragma unroll
    for (int i = 0; i < 8; ++i) p[i] = (short)f2bf(src[(size_t)(kbase + i) * UU + u]);
    *reinterpret_cast<short8*>(out + (size_t)tid * 8) = p;
}

// ---------------------------------------------------------------------------
__global__ __launch_bounds__(256) void init_hbf(const float* __restrict__ h0,
                                                unsigned short* __restrict__ hb)
{
    int i = blockIdx.x * 256 + threadIdx.x;  // 65536
    hb[i] = f2bf(h0[i & (UU - 1)]);
}

// ---------------------------------------------------------------------------
// Phase 1: xw = x @ [fw|iw|cw|ow] + bias, MFMA bf16, bf16 output.
// Output layout: xw[t][ublk(64)][b(64)][g(4)][u16(16)]
// ---------------------------------------------------------------------------
__global__ __launch_bounds__(256) void gemm_xw(
    const float* __restrict__ x, const short* __restrict__ wpk,
    const float* __restrict__ fb, const float* __restrict__ ib,
    const float* __restrict__ cb, const float* __restrict__ ob,
    unsigned short* __restrict__ xw)
{
    __shared__ short As[128 * 40];
    __shared__ short Bs[8 * 512];

    const int tid = threadIdx.x;
    const int lane = tid & 63;
    const int wid = tid >> 6;
    const int wr = wid >> 1, wc = wid & 1;
    const int n0 = blockIdx.x << 7;
    const int m0 = blockIdx.y << 7;
    const int n16b = n0 >> 4;

    const int srow = tid >> 1;
    const int kh = tid & 1;
    const float* __restrict__ xrow = x + (size_t)(m0 + srow) * DD + kh * 16;
    const short* __restrict__ wsrc =
        wpk + ((size_t)(n16b + (tid >> 5)) * 32) * 512 + (size_t)(tid & 31) * 16;

    f32x4 acc[4][4];
#pragma unroll
    for (int i = 0; i < 4; ++i)
#pragma unroll
        for (int j = 0; j < 4; ++j) acc[i][j] = (f32x4){0.f, 0.f, 0.f, 0.f};

    const int aoff = (wr * 64 + (lane & 15)) * 40 + (lane >> 4) * 8;
    const int boff = (wc * 4) * 512 + lane * 8;

    for (int kb = 0; kb < 32; ++kb) {
        const float4* xp = reinterpret_cast<const float4*>(xrow + kb * 32);
        float4 v0 = xp[0], v1 = xp[1], v2 = xp[2], v3 = xp[3];
        short8 p0, p1;
        p0[0] = (short)f2bf(v0.x); p0[1] = (short)f2bf(v0.y);
        p0[2] = (short)f2bf(v0.z); p0[3] = (short)f2bf(v0.w);
        p0[4] = (short)f2bf(v1.x); p0[5] = (short)f2bf(v1.y);
        p0[6] = (short)f2bf(v1.z); p0[7] = (short)f2bf(v1.w);
        p1[0] = (short)f2bf(v2.x); p1[1] = (short)f2bf(v2.y);
        p1[2] = (short)f2bf(v2.z); p1[3] = (short)f2bf(v2.w);
        p1[4] = (short)f2bf(v3.x); p1[5] = (short)f2bf(v3.y);
        p1[6] = (short)f2bf(v3.z); p1[7] = (short)f2bf(v3.w);
        *reinterpret_cast<short8*>(&As[srow * 40 + kh * 16]) = p0;
        *reinterpret_cast<short8*>(&As[srow * 40 + kh * 16 + 8]) = p1;

        const short8* ws8 = reinterpret_cast<const short8*>(wsrc + (size_t)kb * 512);
        short8 b0v = ws8[0], b1v = ws8[1];
        *reinterpret_cast<short8*>(&Bs[tid * 16]) = b0v;
        *reinterpret_cast<short8*>(&Bs[tid * 16 + 8]) = b1v;
        __syncthreads();

        short8 af[4], bfr[4];
#pragma unroll
        for (int fi = 0; fi < 4; ++fi)
            af[fi] = *reinterpret_cast<const short8*>(&As[aoff + fi * 640]);
#pragma unroll
        for (int fj = 0; fj < 4; ++fj)
            bfr[fj] = *reinterpret_cast<const short8*>(&Bs[boff + fj * 512]);
#pragma unroll
        for (int fi = 0; fi < 4; ++fi)
#pragma unroll
            for (int fj = 0; fj < 4; ++fj)
                acc[fi][fj] = __builtin_amdgcn_mfma_f32_16x16x32_bf16(
                    af[fi], bfr[fj], acc[fi][fj], 0, 0, 0);
        __syncthreads();
    }

    const int g = n0 >> 10;
    const float* __restrict__ bias = (g == 0) ? fb : (g == 1) ? ib : (g == 2) ? cb : ob;
#pragma unroll
    for (int fi = 0; fi < 4; ++fi) {
#pragma unroll
        for (int fj = 0; fj < 4; ++fj) {
            int n = n0 + wc * 64 + fj * 16 + (lane & 15);
            int uc = n & 1023;
            int ub = uc >> 4, ul = uc & 15;
            float bv = bias[uc];
#pragma unroll
            for (int r = 0; r < 4; ++r) {
                int row = m0 + wr * 64 + fi * 16 + (lane >> 4) * 4 + r;
                int b = row >> 9, t = row & 511;
                float v = acc[fi][fj][r] + bv;
                size_t off = (((size_t)t * 64 + ub) * BB + b) * 64 + g * 16 + ul;
                xw[off] = f2bf(v);
            }
        }
    }
}

// ---------------------------------------------------------------------------
// One phase of the pipelined two-chain scan. vs r14:
//  - per-wave BYTE flags (word per (t,mz,ub), byte = wave); consumer polls
//    word==0x01010101 -> no cross-wave coordination to fire.
//  - deferred flag firing: each wave fires its byte for the PREVIOUS phase's
//    chain at the START of this phase after a private vmcnt(0) (its own y/h
//    stores only; per-wave stall, not a collective barrier drain).
//  - end-of-phase barrier is a raw s_barrier; only wave 1 pre-drains its DMA
//    with a counted vmcnt(2) (leaves its own h/y stores in flight).
//  - h-store unconditional (slot t+1 <= TT exists) -> uniform vmcnt counts;
//    h-store issued BEFORE y-math (h is the cross-block critical path).
// ---------------------------------------------------------------------------
#define PHASE(MZ, R0, HLS, GBUF, HOWN, OMZ, OHLS, DO_POLL, POLL_T, DO_FLAG, F_MZ, F_T) \
  do {                                                                             \
    if (DO_FLAG) {                                                                 \
      asm volatile("s_waitcnt vmcnt(0)" ::: "memory");                             \
      if (lane == 0)                                                               \
        __hip_atomic_store(                                                        \
            (unsigned char*)flg + ((((size_t)(F_T)) * 4 + (F_MZ)) * 64 + ub) * 4 + gi, \
            (unsigned char)1, __ATOMIC_RELAXED, __HIP_MEMORY_SCOPE_AGENT);         \
    }                                                                              \
    const unsigned short* __restrict__ xp =                                        \
        xw + ((size_t)t * 64 + ub) * 4096 + (size_t)((R0) + trow) * 64 + tcol;     \
    float xv0 = bf2f(xp[0]);                                                       \
    float xv1 = bf2f(xp[16]);                                                      \
    float xv2 = bf2f(xp[32]);                                                      \
    float xv3 = bf2f(xp[48]);                                                      \
    f32x4 acc0 = (f32x4){0.f, 0.f, 0.f, 0.f};                                      \
    f32x4 acc1 = (f32x4){0.f, 0.f, 0.f, 0.f};                                      \
    _Pragma("unroll")                                                              \
    for (int kg = 0; kg < 32; kg += 2) {                                           \
      short8 a0 = *reinterpret_cast<const short8*>(&HLS[aoff + kg * 32]);          \
      short8 a1 = *reinterpret_cast<const short8*>(&HLS[aoff + kg * 32 + 32]);     \
      acc0 = __builtin_amdgcn_mfma_f32_16x16x32_bf16(a0, bfr[kg], acc0, 0, 0, 0);  \
      acc1 = __builtin_amdgcn_mfma_f32_16x16x32_bf16(a1, bfr[kg + 1], acc1,        \
                                                     0, 0, 0);                     \
    }                                                                              \
    acc0[0] += acc1[0]; acc0[1] += acc1[1];                                        \
    acc0[2] += acc1[2]; acc0[3] += acc1[3];                                        \
    _Pragma("unroll")                                                              \
    for (int r = 0; r < 4; ++r)                                                    \
      GBUF[gi][(lane >> 4) * 4 + r][lane & 15] = acc0[r];                          \
    if (gi == 1 && (DO_POLL)) {                                                    \
      const unsigned int* fl =                                                     \
          (const unsigned int*)flg + ((size_t)(POLL_T) * 4 + (OMZ)) * 64 + lane;   \
      unsigned int v;                                                              \
      do {                                                                         \
        v = __hip_atomic_load(fl, __ATOMIC_RELAXED, __HIP_MEMORY_SCOPE_AGENT);     \
        if (v != 0x01010101u) __builtin_amdgcn_s_sleep(1);                         \
      } while (v != 0x01010101u);                                                  \
      asm volatile("" ::: "memory");                                               \
      const unsigned short* hc = hrot + (size_t)(POLL_T) * (BB * UU)               \
                                 + ((size_t)(OMZ) << 4) * UU                       \
                                 + (size_t)(v - 0x01010101u);                      \
      _Pragma("unroll")                                                            \
      for (int p = 0; p < 32; ++p) {                                               \
        int row = p >> 1, half = p & 1;                                            \
        __builtin_amdgcn_global_load_lds(                                          \
            (const void*)(hc + (size_t)row * 1024 + half * 512 + (size_t)lane * 8),\
            (void*)&OHLS[row * 1032 + half * 512], 16, 0, 16);                     \
      }                                                                            \
    }                                                                              \
    asm volatile("s_waitcnt lgkmcnt(0)" ::: "memory");                             \
    __builtin_amdgcn_s_barrier();                                                  \
    asm volatile("" ::: "memory");                                                 \
    {                                                                              \
      float gf  = GBUF[0][trow][tcol] + xv0;                                       \
      float gii = GBUF[1][trow][tcol] + xv1;                                       \
      float gc  = GBUF[2][trow][tcol] + xv2;                                       \
      float go  = GBUF[3][trow][tcol] + xv3;                                       \
      float h1  = fsig(gf) * (HOWN) + fsig(gii) * ftanh(gc);                       \
      (HOWN) = h1;                                                                 \
      unsigned int hb16 = f2bf(h1);                                                \
      unsigned int n1 = __shfl_down(hb16, 1);                                      \
      unsigned int n2 = __shfl_down(hb16, 2);                                      \
      unsigned int n3 = __shfl_down(hb16, 3);                                      \
      if ((lane & 3) == 0) {      /* unconditional in t: slot t+1 <= TT exists */  \
        unsigned long long pv =                                                    \
            (unsigned long long)(hb16 | (n1 << 16)) |                              \
            ((unsigned long long)(n2 | (n3 << 16)) << 32);                         \
        unsigned short* dst = hrot + (size_t)(t + 1) * (BB * UU)                   \
                              + (size_t)((R0) + trow) * UU + u0 + tcol;            \
        __hip_atomic_store(reinterpret_cast<ull*>(dst), pv,                        \
                           __ATOMIC_RELAXED, __HIP_MEMORY_SCOPE_AGENT);            \
      }                                                                            \
      y[((size_t)((R0) + trow) * TT + t) * UU + u0 + tcol] = fsig(go) * ftanh(h1); \
    }                                                                              \
    if (gi == 1 && (DO_POLL))                                                      \
      asm volatile("s_waitcnt vmcnt(2)" ::: "memory");  /* drain DMA, not stores */\
    __builtin_amdgcn_s_barrier();                                                  \
    asm volatile("" ::: "memory");                                                 \
  } while (0)

// ---------------------------------------------------------------------------
// Phase 2: persistent scan, two chains per block, alternating phases with
// cross-phase DMA pipelining + counted-vmcnt deferred flags.
// Grid 128 = 2 chain-pairs x 64 u-blocks; block = 4 waves (wave = gate).
// ---------------------------------------------------------------------------
__global__ __launch_bounds__(256, 1) void lstm_scan(
    const unsigned short* __restrict__ xw, const float* __restrict__ h0,
    unsigned short* __restrict__ hrot,     // [TT+1][64][1024] bf16 rotating
    const short* __restrict__ upk,
    float* __restrict__ y, unsigned int* __restrict__ flg)  // [TT+1][4][64] words
{
    __shared__ unsigned short hlsA[16 * 1032 + 8];
    __shared__ unsigned short hlsB[16 * 1032 + 8];
    __shared__ float gbufA[4][16][20];
    __shared__ float gbufB[4][16][20];

    const int tid = threadIdx.x;
    const int lane = tid & 63;
    const int gi = tid >> 6;              // wave = gate
    const int z  = blockIdx.x >> 6;
    const int ub = blockIdx.x & 63;
    const int mzA = z * 2, mzB = z * 2 + 1;
    const int r0A = mzA << 4, r0B = mzB << 4;
    const int u0 = ub << 4;

    const short* __restrict__ bsrc =
        upk + ((size_t)(gi * 64 + ub) * 32) * 512 + (size_t)lane * 8;
    short8 bfr[32];
#pragma unroll
    for (int kb = 0; kb < 32; ++kb)
        bfr[kb] = *reinterpret_cast<const short8*>(bsrc + (size_t)kb * 512);

    const int aoff = (lane & 15) * 1032 + (lane >> 4) * 8;
    const int trow = tid >> 4, tcol = tid & 15;

    float h_ownA = h0[u0 + tcol];
    float h_ownB = h_ownA;

    // prologue: wave 1 stages both chains' slot-0 tiles; full sync drains.
    if (gi == 1) {
#pragma unroll
        for (int p = 0; p < 32; ++p) {
            int row = p >> 1, half = p & 1;
            __builtin_amdgcn_global_load_lds(
                (const void*)(hrot + (size_t)r0A * UU + (size_t)row * 1024
                              + half * 512 + (size_t)lane * 8),
                (void*)&hlsA[row * 1032 + half * 512], 16, 0, 16);
            __builtin_amdgcn_global_load_lds(
                (const void*)(hrot + (size_t)r0B * UU + (size_t)row * 1024
                              + half * 512 + (size_t)lane * 8),
                (void*)&hlsB[row * 1032 + half * 512], 16, 0, 16);
        }
    }
    __syncthreads();

    for (int t = 0; t < TT; ++t) {
        // phase A(t): fires flagB(t) (h_B(t) stored in B(t-1)); polls B(t)
        PHASE(mzA, r0A, hlsA, gbufA, h_ownA, mzB, hlsB, (t >= 1), t,
              (t >= 1), mzB, t);
        // phase B(t): fires flagA(t+1) (h_A(t+1) stored in A(t)); polls A(t+1)
        PHASE(mzB, r0B, hlsB, gbufB, h_ownB, mzA, hlsA, (t + 1 < TT), t + 1,
              1, mzA, t + 1);
    }
}

// ---------------------------------------------------------------------------
extern "C" void kernel_launch(void* const* d_in, const int* in_sizes, int n_in,
                              void* d_out, int out_size, void* d_ws, size_t ws_size,
                              hipStream_t stream)
{
    const float* x  = (const float*)d_in[0];
    const float* fw = (const float*)d_in[1];
    const float* fu = (const float*)d_in[2];
    const float* fb = (const float*)d_in[3];
    const float* iw = (const float*)d_in[4];
    const float* iu = (const float*)d_in[5];
    const float* ib = (const float*)d_in[6];
    const float* cw = (const float*)d_in[7];
    const float* cu = (const float*)d_in[8];
    const float* cb = (const float*)d_in[9];
    const float* ow = (const float*)d_in[10];
    const float* ou = (const float*)d_in[11];
    const float* ob = (const float*)d_in[12];
    const float* h0 = (const float*)d_in[13];
    float* y = (float*)d_out;

    const size_t xw_elems = (size_t)TT * BB * 4 * UU;       // 134,217,728
    const size_t pk_elems = (size_t)4 * 1024 * 1024;        // shorts per packed W
    const size_t hrot_elems = (size_t)(TT + 1) * BB * UU;

    char* wsb = (char*)d_ws;
    unsigned short* xw = (unsigned short*)wsb;
    short* upk = (short*)(wsb + xw_elems * 2);
    short* wpk = upk + pk_elems;
    unsigned short* hrot = (unsigned short*)(wpk + pk_elems);
    unsigned int* flg = (unsigned int*)(hrot + hrot_elems);

    pack_w<<<2048, 256, 0, stream>>>(fu, iu, cu, ou, upk);
    pack_w<<<2048, 256, 0, stream>>>(fw, iw, cw, ow, wpk);
    init_hbf<<<256, 256, 0, stream>>>(h0, hrot);
    gemm_xw<<<dim3(32, 256), 256, 0, stream>>>(x, wpk, fb, ib, cb, ob, xw);
    hipMemsetAsync(flg, 0, (size_t)(TT + 1) * 4 * 64 * sizeof(unsigned int), stream);

    lstm_scan<<<128, 256, 0, stream>>>(xw, h0, hrot, upk, y, flg);
}

// Round 16
// 2234.539 us; speedup vs baseline: 2.4343x; 2.4343x over previous
//
#include <hip/hip_runtime.h>
#include <hip/hip_bf16.h>

#define BB 64
#define TT 512
#define DD 1024
#define UU 1024

typedef __attribute__((ext_vector_type(8))) short short8;
typedef __attribute__((ext_vector_type(4))) float f32x4;
typedef unsigned long long ull;

static __device__ __forceinline__ unsigned short f2bf(float f) {
    unsigned int u = __float_as_uint(f);
    unsigned int r = (u + 0x7fffu + ((u >> 16) & 1u)) >> 16;   // RNE
    return (unsigned short)r;
}
static __device__ __forceinline__ float bf2f(unsigned short s) {
    return __uint_as_float(((unsigned int)s) << 16);
}
static __device__ __forceinline__ float fsig(float x) {
    return 1.0f / (1.0f + __expf(-x));
}
static __device__ __forceinline__ float ftanh(float x) {
    float e = __expf(-2.0f * fabsf(x));
    float r = (1.0f - e) / (1.0f + e);
    return __builtin_copysignf(r, x);
}

// ---------------------------------------------------------------------------
// Pack a logical (1024 x 4096) weight into MFMA B-fragment layout (see r2).
// ---------------------------------------------------------------------------
__global__ __launch_bounds__(256) void pack_w(
    const float* __restrict__ w0, const float* __restrict__ w1,
    const float* __restrict__ w2, const float* __restrict__ w3,
    short* __restrict__ out)
{
    int tid = blockIdx.x * 256 + threadIdx.x;
    int lane = tid & 63;
    int kb = (tid >> 6) & 31;
    int n16 = tid >> 11;
    int col = (n16 << 4) + (lane & 15);
    int g = col >> 10, u = col & 1023;
    const float* __restrict__ src = (g == 0) ? w0 : (g == 1) ? w1 : (g == 2) ? w2 : w3;
    int kbase = kb * 32 + ((lane >> 4) << 3);
    short8 p;
#pragma unroll
    for (int i = 0; i < 8; ++i) p[i] = (short)f2bf(src[(size_t)(kbase + i) * UU + u]);
    *reinterpret_cast<short8*>(out + (size_t)tid * 8) = p;
}

// ---------------------------------------------------------------------------
__global__ __launch_bounds__(256) void init_hbf(const float* __restrict__ h0,
                                                unsigned short* __restrict__ hb)
{
    int i = blockIdx.x * 256 + threadIdx.x;  // 65536
    hb[i] = f2bf(h0[i & (UU - 1)]);
}

// ---------------------------------------------------------------------------
// Convert x (f32, row-major 32768x1024) to bf16 once. 16384 blocks x 256 thr,
// 8 elems/thread.
// ---------------------------------------------------------------------------
__global__ __launch_bounds__(256) void cvt_x(const float* __restrict__ x,
                                             unsigned short* __restrict__ xb)
{
    size_t i = ((size_t)blockIdx.x * 256 + threadIdx.x) * 8;
    float4 v0 = *reinterpret_cast<const float4*>(x + i);
    float4 v1 = *reinterpret_cast<const float4*>(x + i + 4);
    short8 p;
    p[0] = (short)f2bf(v0.x); p[1] = (short)f2bf(v0.y);
    p[2] = (short)f2bf(v0.z); p[3] = (short)f2bf(v0.w);
    p[4] = (short)f2bf(v1.x); p[5] = (short)f2bf(v1.y);
    p[6] = (short)f2bf(v1.z); p[7] = (short)f2bf(v1.w);
    *reinterpret_cast<short8*>(xb + i) = p;
}

// ---------------------------------------------------------------------------
// Phase 1: xw = x_bf @ [fw|iw|cw|ow] + bias, MFMA bf16, bf16 output.
// Both tiles staged via global_load_lds (width 16). A-tile uses a per-lane
// XOR-swizzled GLOBAL gather (granule g = (lane&3)^(row&3)) with linear LDS
// dest, so fragment ds_read_b128s are 2-way (free) instead of 8-way.
// Output layout: xw[t][ublk(64)][b(64)][g(4)][u16(16)]
// ---------------------------------------------------------------------------
__global__ __launch_bounds__(256) void gemm_xw(
    const unsigned short* __restrict__ xb, const short* __restrict__ wpk,
    const float* __restrict__ fb, const float* __restrict__ ib,
    const float* __restrict__ cb, const float* __restrict__ ob,
    unsigned short* __restrict__ xw)
{
    __shared__ short As2[128 * 32];   // 8 KB, swizzled granules
    __shared__ short Bs[8 * 512];     // 8 KB

    const int tid = threadIdx.x;
    const int lane = tid & 63;
    const int wid = tid >> 6;
    const int wr = wid >> 1, wc = wid & 1;
    const int n0 = blockIdx.x << 7;
    const int m0 = blockIdx.y << 7;
    const int n16b = n0 >> 4;

    f32x4 acc[4][4];
#pragma unroll
    for (int i = 0; i < 4; ++i)
#pragma unroll
        for (int j = 0; j < 4; ++j) acc[i][j] = (f32x4){0.f, 0.f, 0.f, 0.f};

    // A-frag offset (shorts): row R = wr*64 + fi*16 + (lane&15); R&3 == lane&3
    const int aoff = (wr * 64 + (lane & 15)) * 32 + (((lane >> 4) ^ (lane & 3)) << 3);
    const int boff = (wc * 4) * 512 + lane * 8;

    // DMA chunk geometry (per wave: A-chunks 2w,2w+1 and B-chunks 2w,2w+1)
    const int c0 = wid << 1;

    for (int kb = 0; kb < 32; ++kb) {
#pragma unroll
        for (int j = 0; j < 2; ++j) {
            int c = c0 + j;
            int row = (c << 4) + (lane >> 2);
            int g = (lane & 3) ^ (row & 3);
            __builtin_amdgcn_global_load_lds(
                (const void*)(xb + (size_t)(m0 + row) * DD + kb * 32 + g * 8),
                (void*)&As2[c * 512], 16, 0, 0);
            __builtin_amdgcn_global_load_lds(
                (const void*)(wpk + ((size_t)(n16b + c) * 32 + kb) * 512 + (size_t)lane * 8),
                (void*)&Bs[c * 512], 16, 0, 0);
        }
        asm volatile("s_waitcnt vmcnt(0)" ::: "memory");
        __syncthreads();

        short8 af[4], bfr[4];
#pragma unroll
        for (int fi = 0; fi < 4; ++fi)
            af[fi] = *reinterpret_cast<const short8*>(&As2[aoff + fi * 512]);
#pragma unroll
        for (int fj = 0; fj < 4; ++fj)
            bfr[fj] = *reinterpret_cast<const short8*>(&Bs[boff + fj * 512]);
#pragma unroll
        for (int fi = 0; fi < 4; ++fi)
#pragma unroll
            for (int fj = 0; fj < 4; ++fj)
                acc[fi][fj] = __builtin_amdgcn_mfma_f32_16x16x32_bf16(
                    af[fi], bfr[fj], acc[fi][fj], 0, 0, 0);
        __syncthreads();
    }

    const int g = n0 >> 10;
    const float* __restrict__ bias = (g == 0) ? fb : (g == 1) ? ib : (g == 2) ? cb : ob;
#pragma unroll
    for (int fi = 0; fi < 4; ++fi) {
#pragma unroll
        for (int fj = 0; fj < 4; ++fj) {
            int n = n0 + wc * 64 + fj * 16 + (lane & 15);
            int uc = n & 1023;
            int ub = uc >> 4, ul = uc & 15;
            float bv = bias[uc];
#pragma unroll
            for (int r = 0; r < 4; ++r) {
                int row = m0 + wr * 64 + fi * 16 + (lane >> 4) * 4 + r;
                int b = row >> 9, t = row & 511;
                float v = acc[fi][fj][r] + bv;
                size_t off = (((size_t)t * 64 + ub) * BB + b) * 64 + g * 16 + ul;
                xw[off] = f2bf(v);
            }
        }
    }
}

// ---------------------------------------------------------------------------
// One phase of the pipelined two-chain scan (r14-good, verbatim).
// Chain MZ computes step t; wave 1 additionally polls+issues the DMA for
// chain OMZ's step POLL_T into OHLS. Barriers: one raw lgkm-only s_barrier
// (gbuf->tail; does NOT drain wave1's in-flight DMA) + one __syncthreads
// (drains stores AND wave1's DMA; latency overlaps the tail). Flag fires
// after the full drain.
// ---------------------------------------------------------------------------
#define PHASE(MZ, R0, HLS, GBUF, HOWN, OMZ, OHLS, DO_POLL, POLL_T)                 \
  do {                                                                             \
    const unsigned short* __restrict__ xp =                                        \
        xw + ((size_t)t * 64 + ub) * 4096 + (size_t)((R0) + trow) * 64 + tcol;     \
    float xv0 = bf2f(xp[0]);                                                       \
    float xv1 = bf2f(xp[16]);                                                      \
    float xv2 = bf2f(xp[32]);                                                      \
    float xv3 = bf2f(xp[48]);                                                      \
    f32x4 acc0 = (f32x4){0.f, 0.f, 0.f, 0.f};                                      \
    f32x4 acc1 = (f32x4){0.f, 0.f, 0.f, 0.f};                                      \
    _Pragma("unroll")                                                              \
    for (int kg = 0; kg < 32; kg += 2) {                                           \
      short8 a0 = *reinterpret_cast<const short8*>(&HLS[aoff + kg * 32]);          \
      short8 a1 = *reinterpret_cast<const short8*>(&HLS[aoff + kg * 32 + 32]);     \
      acc0 = __builtin_amdgcn_mfma_f32_16x16x32_bf16(a0, bfr[kg], acc0, 0, 0, 0);  \
      acc1 = __builtin_amdgcn_mfma_f32_16x16x32_bf16(a1, bfr[kg + 1], acc1,        \
                                                     0, 0, 0);                     \
    }                                                                              \
    acc0[0] += acc1[0]; acc0[1] += acc1[1];                                        \
    acc0[2] += acc1[2]; acc0[3] += acc1[3];                                        \
    _Pragma("unroll")                                                              \
    for (int r = 0; r < 4; ++r)                                                    \
      GBUF[gi][(lane >> 4) * 4 + r][lane & 15] = acc0[r];                          \
    if (gi == 1 && (DO_POLL)) {                                                    \
      const int* fl = flg + ((size_t)(POLL_T) * 4 + (OMZ)) * 64 + lane;            \
      int v;                                                                       \
      do {                                                                         \
        v = __hip_atomic_load(fl, __ATOMIC_RELAXED, __HIP_MEMORY_SCOPE_AGENT);     \
        if (v == 0) __builtin_amdgcn_s_sleep(1);                                   \
      } while (v == 0);                                                            \
      asm volatile("" ::: "memory");                                               \
      const unsigned short* hc = hrot + (size_t)(POLL_T) * (BB * UU)               \
                                 + ((size_t)(OMZ) << 4) * UU + (size_t)(v - 1);    \
      _Pragma("unroll")                                                            \
      for (int p = 0; p < 32; ++p) {                                               \
        int row = p >> 1, half = p & 1;                                            \
        __builtin_amdgcn_global_load_lds(                                          \
            (const void*)(hc + (size_t)row * 1024 + half * 512 + (size_t)lane * 8),\
            (void*)&OHLS[row * 1032 + half * 512], 16, 0, 16);                     \
      }                                                                            \
    }                                                                              \
    asm volatile("s_waitcnt lgkmcnt(0)" ::: "memory");                             \
    __builtin_amdgcn_s_barrier();                                                  \
    asm volatile("" ::: "memory");                                                 \
    {                                                                              \
      float gf  = GBUF[0][trow][tcol] + xv0;                                       \
      float gii = GBUF[1][trow][tcol] + xv1;                                       \
      float gc  = GBUF[2][trow][tcol] + xv2;                                       \
      float go  = GBUF[3][trow][tcol] + xv3;                                       \
      float h1  = fsig(gf) * (HOWN) + fsig(gii) * ftanh(gc);                       \
      (HOWN) = h1;                                                                 \
      y[((size_t)((R0) + trow) * TT + t) * UU + u0 + tcol] = fsig(go) * ftanh(h1); \
      unsigned int hb16 = f2bf(h1);                                                \
      unsigned int n1 = __shfl_down(hb16, 1);                                      \
      unsigned int n2 = __shfl_down(hb16, 2);                                      \
      unsigned int n3 = __shfl_down(hb16, 3);                                      \
      if (t < TT - 1 && (lane & 3) == 0) {                                         \
        unsigned long long pv =                                                    \
            (unsigned long long)(hb16 | (n1 << 16)) |                              \
            ((unsigned long long)(n2 | (n3 << 16)) << 32);                         \
        unsigned short* dst = hrot + (size_t)(t + 1) * (BB * UU)                   \
                              + (size_t)((R0) + trow) * UU + u0 + tcol;            \
        __hip_atomic_store(reinterpret_cast<ull*>(dst), pv,                        \
                           __ATOMIC_RELAXED, __HIP_MEMORY_SCOPE_AGENT);            \
      }                                                                            \
    }                                                                              \
    __syncthreads();   /* drains h/y stores AND wave1's DMA; barrier */            \
    if (t < TT - 1 && gi == 0 && lane == 0)                                        \
      __hip_atomic_store(flg + ((size_t)(t + 1) * 4 + (MZ)) * 64 + ub, 1,          \
                         __ATOMIC_RELAXED, __HIP_MEMORY_SCOPE_AGENT);              \
  } while (0)

// ---------------------------------------------------------------------------
// Phase 2: persistent scan, two chains per block, alternating phases with
// cross-phase DMA pipelining (r14-good). Grid 128 = 2 chain-pairs x 64
// u-blocks; block = 4 waves (wave = gate, U B-frags in VGPRs).
// ---------------------------------------------------------------------------
__global__ __launch_bounds__(256, 1) void lstm_scan(
    const unsigned short* __restrict__ xw, const float* __restrict__ h0,
    unsigned short* __restrict__ hrot,     // [TT+1][64][1024] bf16 rotating
    const short* __restrict__ upk,
    float* __restrict__ y, int* __restrict__ flg)   // [TT+1][4][64]
{
    __shared__ unsigned short hlsA[16 * 1032 + 8];
    __shared__ unsigned short hlsB[16 * 1032 + 8];
    __shared__ float gbufA[4][16][20];
    __shared__ float gbufB[4][16][20];

    const int tid = threadIdx.x;
    const int lane = tid & 63;
    const int gi = tid >> 6;              // wave = gate
    const int z  = blockIdx.x >> 6;
    const int ub = blockIdx.x & 63;
    const int mzA = z * 2, mzB = z * 2 + 1;
    const int r0A = mzA << 4, r0B = mzB << 4;
    const int u0 = ub << 4;

    const short* __restrict__ bsrc =
        upk + ((size_t)(gi * 64 + ub) * 32) * 512 + (size_t)lane * 8;
    short8 bfr[32];
#pragma unroll
    for (int kb = 0; kb < 32; ++kb)
        bfr[kb] = *reinterpret_cast<const short8*>(bsrc + (size_t)kb * 512);

    const int aoff = (lane & 15) * 1032 + (lane >> 4) * 8;
    const int trow = tid >> 4, tcol = tid & 15;

    float h_ownA = h0[u0 + tcol];
    float h_ownB = h_ownA;

    // prologue: wave 1 stages both chains' slot-0 tiles; full sync drains.
    if (gi == 1) {
#pragma unroll
        for (int p = 0; p < 32; ++p) {
            int row = p >> 1, half = p & 1;
            __builtin_amdgcn_global_load_lds(
                (const void*)(hrot + (size_t)r0A * UU + (size_t)row * 1024
                              + half * 512 + (size_t)lane * 8),
                (void*)&hlsA[row * 1032 + half * 512], 16, 0, 16);
            __builtin_amdgcn_global_load_lds(
                (const void*)(hrot + (size_t)r0B * UU + (size_t)row * 1024
                              + half * 512 + (size_t)lane * 8),
                (void*)&hlsB[row * 1032 + half * 512], 16, 0, 16);
        }
    }
    __syncthreads();

    for (int t = 0; t < TT; ++t) {
        PHASE(mzA, r0A, hlsA, gbufA, h_ownA, mzB, hlsB, (t >= 1), t);
        PHASE(mzB, r0B, hlsB, gbufB, h_ownB, mzA, hlsA, (t + 1 < TT), t + 1);
    }
}

// ---------------------------------------------------------------------------
extern "C" void kernel_launch(void* const* d_in, const int* in_sizes, int n_in,
                              void* d_out, int out_size, void* d_ws, size_t ws_size,
                              hipStream_t stream)
{
    const float* x  = (const float*)d_in[0];
    const float* fw = (const float*)d_in[1];
    const float* fu = (const float*)d_in[2];
    const float* fb = (const float*)d_in[3];
    const float* iw = (const float*)d_in[4];
    const float* iu = (const float*)d_in[5];
    const float* ib = (const float*)d_in[6];
    const float* cw = (const float*)d_in[7];
    const float* cu = (const float*)d_in[8];
    const float* cb = (const float*)d_in[9];
    const float* ow = (const float*)d_in[10];
    const float* ou = (const float*)d_in[11];
    const float* ob = (const float*)d_in[12];
    const float* h0 = (const float*)d_in[13];
    float* y = (float*)d_out;

    const size_t xw_elems = (size_t)TT * BB * 4 * UU;       // 134,217,728
    const size_t pk_elems = (size_t)4 * 1024 * 1024;        // shorts per packed W
    const size_t hrot_elems = (size_t)(TT + 1) * BB * UU;

    char* wsb = (char*)d_ws;
    unsigned short* xw = (unsigned short*)wsb;
    short* upk = (short*)(wsb + xw_elems * 2);
    short* wpk = upk + pk_elems;
    unsigned short* hrot = (unsigned short*)(wpk + pk_elems);
    int* flg = (int*)(hrot + hrot_elems);

    // x_bf (64 MB) aliases hrot slots 1..512: written by cvt_x, fully consumed
    // by gemm_xw BEFORE lstm_scan's first h-store touches slot 1 (same stream).
    unsigned short* xb = hrot + (size_t)BB * UU;

    pack_w<<<2048, 256, 0, stream>>>(fu, iu, cu, ou, upk);
    pack_w<<<2048, 256, 0, stream>>>(fw, iw, cw, ow, wpk);
    init_hbf<<<256, 256, 0, stream>>>(h0, hrot);
    cvt_x<<<16384, 256, 0, stream>>>(x, xb);
    gemm_xw<<<dim3(32, 256), 256, 0, stream>>>(xb, wpk, fb, ib, cb, ob, xw);
    hipMemsetAsync(flg, 0, (size_t)(TT + 1) * 4 * 64 * sizeof(int), stream);

    lstm_scan<<<128, 256, 0, stream>>>(xw, h0, hrot, upk, y, flg);
}